// Round 3
// baseline (4113.489 us; speedup 1.0000x reference)
//
#include <hip/hip_runtime.h>
#include <hip/hip_bf16.h>
#include <math.h>

#define Bn   4
#define CINn 16
#define HIDn 16
#define Tn   31
#define Hn   128
#define Wn   128
#define OCn  64
#define TAPSn 27

#define WH   64          // w elements per block (half row)
#define WHP  68          // padded LDS stride (66 halo -> 68)
#define HALO 66

// Repack W[oc][cin][tap] -> Wr[q][tap][cin][16] where 16 = hdl*4+gate,
// oc = gate*16 + q*4 + hdl. Wave (fixed q) reads one contiguous 64B scalar
// chunk per (tap,cin). Bias -> Wr[27648 + q*16 + j].
__global__ void repack_w_kernel(const float* __restrict__ W, const float* __restrict__ b,
                                float* __restrict__ Wr) {
    int idx = blockIdx.x * blockDim.x + threadIdx.x;
    if (idx < OCn * CINn * TAPSn) {
        int j    = idx & 15;            // hdl*4+gate
        int hdl  = j >> 2;
        int gate = j & 3;
        int cin  = (idx >> 4) & 15;
        int tq   = idx >> 8;            // q*27+tap
        int tap  = tq % 27;
        int q    = tq / 27;
        int oc   = gate * 16 + q * 4 + hdl;
        Wr[idx] = W[(oc * CINn + cin) * TAPSn + tap];
    } else if (idx < OCn * CINn * TAPSn + 64) {
        int k    = idx - OCn * CINn * TAPSn;
        int j    = k & 15;
        int q    = k >> 4;
        int hdl  = j >> 2;
        int gate = j & 3;
        Wr[idx] = b[gate * 16 + q * 4 + hdl];
    }
}

__device__ __forceinline__ float sigmoidf_(float x) { return 1.f / (1.f + __expf(-x)); }
__device__ __forceinline__ float tanhf_(float x)    { return 2.f / (1.f + __expf(-2.f * x)) - 1.f; }

// Block = (b, h, whalf): 256 threads = 64 w x 4 oc-quarters. Thread owns hid
// channels 4q..4q+3 (all 4 gates) -> g[16] accumulators, c[4] recurrence local.
// launch_bounds (256,4): VGPR cap = 128 under either waves/EU or blocks/CU
// interpretation of the 2nd arg (R2's (512,4) caused a 28-VGPR spill disaster).
__global__ __launch_bounds__(256, 4)
void qrnn_fused_kernel(const float* __restrict__ X, const float* __restrict__ Wr,
                       float* __restrict__ out) {
    __shared__ __hip_bfloat16 smem[3 * 3 * CINn * WHP];  // 19584 B
    const int tid   = threadIdx.x;
    const int w     = tid & 63;
    const int q     = __builtin_amdgcn_readfirstlane(tid >> 6);  // wave-uniform
    const int whalf = blockIdx.x & 1;
    const int h     = (blockIdx.x >> 1) & 127;
    const int b     = blockIdx.x >> 8;
    const int wbase = whalf * WH;

    const size_t strideT = (size_t)Hn * Wn;        // 16384
    const size_t strideC = (size_t)Tn * strideT;   // 507904
    const float* Xb = X + (size_t)b * CINn * strideC;

    // wave-uniform weight base: [q][tap][cin][16]
    const float* __restrict__ Wq = Wr + (size_t)q * TAPSn * CINn * 16;
    const float* __restrict__ Bq = Wr + OCn * CINn * TAPSn + q * 16;

    // Stage time slice u (rows h-1..h+1, all cin, 66-wide w halo) into slot s.
    auto stage = [&](int u, int s) {
        __hip_bfloat16* sb = smem + s * (3 * CINn * WHP);
        const bool uok = (u >= 0 && u < Tn);
        for (int idx = tid; idx < 3 * CINn * HALO; idx += 256) {
            int wi  = idx % HALO;         // 0..65 -> gw = wbase+wi-1
            int rc  = idx / HALO;
            int cin = rc & 15;
            int r   = rc >> 4;            // row h-1+r
            int hr  = h - 1 + r;
            int gw  = wbase + wi - 1;
            float v = 0.f;
            if (uok && hr >= 0 && hr < Hn && gw >= 0 && gw < Wn)
                v = Xb[(size_t)cin * strideC + (size_t)u * strideT + (size_t)hr * Wn + gw];
            sb[(r * CINn + cin) * WHP + wi] = __float2bfloat16(v);
        }
    };

    float c[4] = {0.f, 0.f, 0.f, 0.f};

    stage(-1, 2);
    stage(0, 0);

    float* outb = out + (size_t)b * HIDn * strideC + (size_t)h * Wn + wbase + w;

    for (int t = 0; t < Tn; t++) {
        stage(t + 1, (t + 1) % 3);   // u=31 stages zeros
        __syncthreads();

        float g[16];
        #pragma unroll
        for (int j = 0; j < 16; j++) g[j] = 0.f;

        const int s0 = (t + 2) % 3;  // slot(t-1)
        const int s1 = t % 3;        // slot(t)
        const int s2 = (t + 1) % 3;  // slot(t+1)

        #pragma unroll
        for (int kd = 0; kd < 3; kd++) {
            const int sl = (kd == 0) ? s0 : (kd == 1) ? s1 : s2;
            const __hip_bfloat16* __restrict__ sbase = smem + sl * (3 * CINn * WHP);
            #pragma unroll
            for (int kh = 0; kh < 3; kh++) {
                #pragma unroll
                for (int kw = 0; kw < 3; kw++) {
                    const __hip_bfloat16* __restrict__ px = sbase + kh * (CINn * WHP) + w + kw;
                    const float* __restrict__ wtap = Wq + (kd * 9 + kh * 3 + kw) * (CINn * 16);
                    for (int cin = 0; cin < CINn; cin++) {
                        float xv = __bfloat162float(px[cin * WHP]);
                        const float* __restrict__ wrow = wtap + cin * 16; // wave-uniform -> s_load
                        #pragma unroll
                        for (int j = 0; j < 16; j++)
                            g[j] = fmaf(wrow[j], xv, g[j]);
                    }
                }
            }
        }

        // activations + recurrence + store (hd = 4q + hdl; j = hdl*4 + gate)
        #pragma unroll
        for (int hdl = 0; hdl < 4; hdl++) {
            float z = tanhf_   (g[hdl * 4 + 0] + Bq[hdl * 4 + 0]);
            float f = sigmoidf_(g[hdl * 4 + 1] + Bq[hdl * 4 + 1]);
            float o = sigmoidf_(g[hdl * 4 + 2] + Bq[hdl * 4 + 2]);
            float i = sigmoidf_(g[hdl * 4 + 3] + Bq[hdl * 4 + 3]);
            c[hdl] = f * c[hdl] + i * z;
            int hd = 4 * q + hdl;
            outb[(size_t)hd * strideC + (size_t)t * strideT] = o * c[hdl];
        }
        __syncthreads();  // protect ring slot reused by next t's stage
    }
}

extern "C" void kernel_launch(void* const* d_in, const int* in_sizes, int n_in,
                              void* d_out, int out_size, void* d_ws, size_t ws_size,
                              hipStream_t stream) {
    const float* X    = (const float*)d_in[0];
    const float* W    = (const float*)d_in[1];
    const float* bias = (const float*)d_in[2];
    float* out = (float*)d_out;
    float* Wr  = (float*)d_ws;   // 27648 + 64 floats

    repack_w_kernel<<<(OCn * CINn * TAPSn + 64 + 255) / 256, 256, 0, stream>>>(W, bias, Wr);

    qrnn_fused_kernel<<<Bn * Hn * 2, 256, 0, stream>>>(X, Wr, out);
}